// Round 3
// baseline (673.581 us; speedup 1.0000x reference)
//
#include <hip/hip_runtime.h>
#include <cstdint>
#include <cstddef>

// ---------------- CSR construction ----------------

__global__ void hist_k(const int* __restrict__ recv, int* __restrict__ hist, int E){
  int i = blockIdx.x*blockDim.x + threadIdx.x;
  if (i < E) atomicAdd(&hist[recv[i]], 1);
}

// block-reduce hist -> partial sums; ALSO does weight folding (fused, it's tiny):
// W1eff[192][128]: rows 0..63 = w0[0:64]; rows 64..191 = Wmsg @ w0[64:128]
// W3eff[192][64]:  rows 0..127 = w2 ; rows 128..191 = W_node
__global__ void s1_k(const int* __restrict__ hist, int* __restrict__ partial, int Nn,
                     const float* __restrict__ Wmsg, const float* __restrict__ w0,
                     const float* __restrict__ w2, const float* __restrict__ Wnode,
                     float* __restrict__ W1eff, float* __restrict__ W3eff){
  __shared__ int sh[256];
  int t = threadIdx.x;
  int i = blockIdx.x*256 + t;
  sh[t] = (i < Nn) ? hist[i] : 0;
  __syncthreads();
  for (int off = 128; off > 0; off >>= 1){
    if (t < off) sh[t] += sh[t + off];
    __syncthreads();
  }
  if (t == 0) partial[blockIdx.x] = sh[0];

  // fused weight prep
  int idx = blockIdx.x*256 + t;
  if (idx < 192*128){
    int r = idx >> 7, j = idx & 127;
    float v;
    if (r < 64) v = w0[r*128 + j];
    else {
      int kk = r - 64;
      float a = 0.f;
      for (int m = 0; m < 64; m++) a = fmaf(Wmsg[kk*64 + m], w0[(64 + m)*128 + j], a);
      v = a;
    }
    W1eff[idx] = v;
  }
  if (idx < 192*64){
    int r = idx >> 6, j = idx & 63;
    W3eff[idx] = (r < 128) ? w2[r*64 + j] : Wnode[(r - 128)*64 + j];
  }
}

// single-wave exclusive scan over nb block sums
__global__ void s2_k(int* __restrict__ partial, int nb){
  int lane = threadIdx.x;  // 64 threads
  int run = 0;
  for (int base = 0; base < nb; base += 64){
    int v = (base + lane < nb) ? partial[base + lane] : 0;
    int x = v;
    #pragma unroll
    for (int off = 1; off < 64; off <<= 1){
      int y = __shfl_up(x, off);
      if (lane >= off) x += y;
    }
    if (base + lane < nb) partial[base + lane] = x - v + run;
    run += __shfl(x, 63);
  }
}

__global__ void s3_k(const int* __restrict__ hist, const int* __restrict__ partial,
                     int* __restrict__ offsets, int* __restrict__ cursor, int Nn){
  __shared__ int sh[256];
  int t = threadIdx.x;
  int i = blockIdx.x*256 + t;
  int v = (i < Nn) ? hist[i] : 0;
  sh[t] = v;
  __syncthreads();
  for (int off = 1; off < 256; off <<= 1){
    int x = (t >= off) ? sh[t - off] : 0;
    __syncthreads();
    sh[t] += x;
    __syncthreads();
  }
  if (i < Nn){
    int excl = sh[t] - v + partial[blockIdx.x];
    offsets[i] = excl;
    cursor[i]  = excl;
  }
}

// packed CSR: (edge index, sender) per slot
__global__ void fill_k(const int* __restrict__ recv, const int* __restrict__ senders,
                       int* __restrict__ cursor, int2* __restrict__ csr_pack, int E){
  int i = blockIdx.x*blockDim.x + threadIdx.x;
  if (i < E){
    int r = recv[i];
    int s = senders[i];
    int pos = atomicAdd(&cursor[r], 1);
    csr_pack[pos] = make_int2(i, s);
  }
}

// ---------------- segment sum writing TRANSPOSED via LDS ----------------
// XT layout [192][N]: rows 0..63 = nodes^T (separate transpose kernel),
// rows 64..127 = S^T (sum of sender rows), rows 128..191 = E^T (sum of edge rows).
// Block: 256 thr = 4 waves; 64 consecutive nodes; each wave 16 nodes serially.
__global__ __launch_bounds__(256) void gather_sum_k(
    const float* __restrict__ nodes, const float* __restrict__ edges,
    const int2* __restrict__ csr_pack, const int* __restrict__ offsets,
    const int* __restrict__ hist, float* __restrict__ XT, int Nn)
{
  __shared__ float tile[128][65];   // rows 0..63 S, 64..127 E; col = local node
  int wid  = threadIdx.x >> 6;
  int lane = threadIdx.x & 63;
  int nblock = blockIdx.x * 64;

  for (int it = 0; it < 16; ++it){
    int nd = nblock + wid*16 + it;
    float sa = 0.f, ea = 0.f;
    if (nd < Nn){
      int start = offsets[nd];
      int cnt   = hist[nd];
      int done = 0;
      while (done < cnt){
        int m = cnt - done; if (m > 64) m = 64;
        int2 pk = make_int2(0, 0);
        if (lane < m) pk = csr_pack[start + done + lane];
        int u = 0;
        for (; u + 4 <= m; u += 4){
          int e0 = __shfl(pk.x, u+0), s0 = __shfl(pk.y, u+0);
          int e1 = __shfl(pk.x, u+1), s1 = __shfl(pk.y, u+1);
          int e2 = __shfl(pk.x, u+2), s2 = __shfl(pk.y, u+2);
          int e3 = __shfl(pk.x, u+3), s3 = __shfl(pk.y, u+3);
          float n0 = nodes[(size_t)s0*64 + lane];
          float n1 = nodes[(size_t)s1*64 + lane];
          float n2 = nodes[(size_t)s2*64 + lane];
          float n3 = nodes[(size_t)s3*64 + lane];
          float g0 = edges[(size_t)e0*64 + lane];
          float g1 = edges[(size_t)e1*64 + lane];
          float g2 = edges[(size_t)e2*64 + lane];
          float g3 = edges[(size_t)e3*64 + lane];
          sa += (n0 + n1) + (n2 + n3);
          ea += (g0 + g1) + (g2 + g3);
        }
        for (; u < m; u++){
          int e0 = __shfl(pk.x, u), s0 = __shfl(pk.y, u);
          sa += nodes[(size_t)s0*64 + lane];
          ea += edges[(size_t)e0*64 + lane];
        }
        done += m;
      }
    }
    int c = wid*16 + it;
    tile[lane][c]      = sa;   // bank = (lane + c) % 32 -> 2-way, free
    tile[64 + lane][c] = ea;
  }
  __syncthreads();

  // coalesced transposed write-out: each wave writes one 64-float row per iter
  for (int r4 = 0; r4 < 128; r4 += 4){
    int r = r4 + wid;
    int n = nblock + lane;
    if (n < Nn) XT[(size_t)(64 + r)*Nn + n] = tile[r][lane];
  }
}

// ---------------- tiled transpose [R][C] -> [C][R] (nodes -> XT rows 0..63) ----------------
__global__ void transpose_k(const float* __restrict__ in, float* __restrict__ out, int R, int C){
  __shared__ float tl[32][33];
  int c0 = blockIdx.x*32, r0 = blockIdx.y*32;
  int tx = threadIdx.x, ty = threadIdx.y;
  #pragma unroll
  for (int i = 0; i < 32; i += 8){
    int r = r0 + ty + i, c = c0 + tx;
    if (r < R && c < C) tl[ty + i][tx] = in[(size_t)r*C + c];
  }
  __syncthreads();
  #pragma unroll
  for (int i = 0; i < 32; i += 8){
    int c = c0 + ty + i, r = r0 + tx;
    if (r < R && c < C) out[(size_t)c*R + r] = tl[tx][ty + i];
  }
}

// ---------------- MLP layers ----------------

__global__ __launch_bounds__(256) void layer1_k(
    const float* __restrict__ XT, const float* __restrict__ W, const float* __restrict__ bias,
    float* __restrict__ outT, int N)
{
  int n  = blockIdx.x*256 + threadIdx.x;
  int jb = blockIdx.y*32;
  if (n >= N) return;
  float acc[32];
  #pragma unroll
  for (int j = 0; j < 32; j++) acc[j] = bias[jb + j];
  for (int k = 0; k < 192; k++){
    float x = XT[(size_t)k*N + n];
    #pragma unroll
    for (int j = 0; j < 32; j++) acc[j] = fmaf(x, W[k*128 + jb + j], acc[j]);
  }
  #pragma unroll
  for (int j = 0; j < 32; j++) outT[(size_t)(jb + j)*N + n] = fmaxf(acc[j], 0.f);
}

__global__ __launch_bounds__(256) void layer2_k(
    const float* __restrict__ inT, const float* __restrict__ W, const float* __restrict__ bias,
    float* __restrict__ outT, int N)
{
  int n  = blockIdx.x*256 + threadIdx.x;
  int jb = blockIdx.y*32;
  if (n >= N) return;
  float acc[32];
  #pragma unroll
  for (int j = 0; j < 32; j++) acc[j] = bias[jb + j];
  for (int k = 0; k < 128; k++){
    float x = inT[(size_t)k*N + n];
    #pragma unroll
    for (int j = 0; j < 32; j++) acc[j] = fmaf(x, W[k*128 + jb + j], acc[j]);
  }
  #pragma unroll
  for (int j = 0; j < 32; j++) outT[(size_t)(jb + j)*N + n] = fmaxf(acc[j], 0.f);
}

__global__ __launch_bounds__(256) void layer3_k(
    const float* __restrict__ X2T, const float* __restrict__ nodesT,
    const float* __restrict__ W, const float* __restrict__ bias,
    const float* __restrict__ ln_scale, const float* __restrict__ ln_bias,
    float* __restrict__ out, int N)
{
  int n = blockIdx.x*256 + threadIdx.x;
  if (n >= N) return;
  float acc[64];
  #pragma unroll
  for (int j = 0; j < 64; j++) acc[j] = bias[j];
  for (int k = 0; k < 128; k++){
    float x = X2T[(size_t)k*N + n];
    #pragma unroll
    for (int j = 0; j < 64; j++) acc[j] = fmaf(x, W[k*64 + j], acc[j]);
  }
  for (int k = 0; k < 64; k++){
    float x = nodesT[(size_t)k*N + n];
    #pragma unroll
    for (int j = 0; j < 64; j++) acc[j] = fmaf(x, W[(128 + k)*64 + j], acc[j]);
  }
  float mu = 0.f;
  #pragma unroll
  for (int j = 0; j < 64; j++) mu += acc[j];
  mu *= (1.f/64.f);
  float var = 0.f;
  #pragma unroll
  for (int j = 0; j < 64; j++){ float d = acc[j] - mu; var = fmaf(d, d, var); }
  var *= (1.f/64.f);
  float inv = rsqrtf(var + 1e-6f);
  float4* o = (float4*)(out + (size_t)n*64);
  #pragma unroll
  for (int q = 0; q < 16; q++){
    float y0 = (acc[4*q+0] - mu)*inv*ln_scale[4*q+0] + ln_bias[4*q+0];
    float y1 = (acc[4*q+1] - mu)*inv*ln_scale[4*q+1] + ln_bias[4*q+1];
    float y2 = (acc[4*q+2] - mu)*inv*ln_scale[4*q+2] + ln_bias[4*q+2];
    float y3 = (acc[4*q+3] - mu)*inv*ln_scale[4*q+3] + ln_bias[4*q+3];
    o[q] = make_float4(y0, y1, y2, y3);
  }
}

// ---------------- launch ----------------

extern "C" void kernel_launch(void* const* d_in, const int* in_sizes, int n_in,
                              void* d_out, int out_size, void* d_ws, size_t ws_size,
                              hipStream_t stream)
{
  const float* nodes   = (const float*)d_in[0];
  const float* edges   = (const float*)d_in[1];
  const int*   senders = (const int*)d_in[2];
  const int*   recv    = (const int*)d_in[3];
  const float* Wmsg    = (const float*)d_in[4];
  const float* Wnode   = (const float*)d_in[5];
  const float* w0      = (const float*)d_in[6];
  const float* b0      = (const float*)d_in[7];
  const float* w1      = (const float*)d_in[8];
  const float* b1      = (const float*)d_in[9];
  const float* w2      = (const float*)d_in[10];
  const float* b2      = (const float*)d_in[11];
  const float* lns     = (const float*)d_in[12];
  const float* lnb     = (const float*)d_in[13];
  float* out = (float*)d_out;

  const int N = in_sizes[0] / 64;
  const int E = in_sizes[2];

  auto align256 = [](size_t x){ return (x + 255) & ~(size_t)255; };
  char* p = (char*)d_ws;
  int* hist    = (int*)p; p += align256((size_t)N*4);
  int* offsets = (int*)p; p += align256((size_t)N*4);
  int* cursor  = (int*)p; p += align256((size_t)N*4);
  int* partial = (int*)p; p += align256(1024);
  int2* csr_pack = (int2*)p; p += align256((size_t)E*8);
  float* W1eff = (float*)p; p += align256((size_t)192*128*4);
  float* W3eff = (float*)p; p += align256((size_t)192*64*4);
  float* XT    = (float*)p; p += align256((size_t)192*N*4);  // [nodesT; S_T; E_T]
  float* bufA  = (float*)p; p += align256((size_t)128*N*4);  // X1_T
  float* bufB  = (float*)p; p += align256((size_t)128*N*4);  // X2_T

  hipMemsetAsync(hist, 0, (size_t)N*4, stream);

  const int gridE = (E + 255)/256;
  const int nb    = (N + 255)/256;

  hist_k<<<gridE, 256, 0, stream>>>(recv, hist, E);
  s1_k<<<nb, 256, 0, stream>>>(hist, partial, N, Wmsg, w0, w2, Wnode, W1eff, W3eff);
  s2_k<<<1, 64, 0, stream>>>(partial, nb);
  s3_k<<<nb, 256, 0, stream>>>(hist, partial, offsets, cursor, N);
  fill_k<<<gridE, 256, 0, stream>>>(recv, senders, cursor, csr_pack, E);

  // nodes^T into XT rows 0..63
  dim3 tb(32, 8);
  transpose_k<<<dim3(2, (N + 31)/32), tb, 0, stream>>>(nodes, XT, N, 64);

  // S^T, E^T into XT rows 64..191 (LDS-staged transposed write)
  gather_sum_k<<<(N + 63)/64, 256, 0, stream>>>(nodes, edges, csr_pack, offsets, hist, XT, N);

  layer1_k<<<dim3(nb, 4), 256, 0, stream>>>(XT, W1eff, b0, bufA, N);
  layer2_k<<<dim3(nb, 4), 256, 0, stream>>>(bufA, w1, b1, bufB, N);
  layer3_k<<<nb, 256, 0, stream>>>(bufB, XT, W3eff, b2, lns, lnb, out, N);
}

// Round 4
// 653.676 us; speedup vs baseline: 1.0305x; 1.0305x over previous
//
#include <hip/hip_runtime.h>
#include <cstdint>
#include <cstddef>

// ---------------- CSR construction ----------------

__global__ void hist_k(const int* __restrict__ recv, int* __restrict__ hist, int E){
  int i = blockIdx.x*blockDim.x + threadIdx.x;
  if (i < E) atomicAdd(&hist[recv[i]], 1);
}

// block-reduce hist -> partial sums; ALSO does weight folding (fused, it's tiny):
// W1eff[192][128]: rows 0..63 = w0[0:64]; rows 64..191 = Wmsg @ w0[64:128]
// W3eff[192][64]:  rows 0..127 = w2 ; rows 128..191 = W_node
__global__ void s1_k(const int* __restrict__ hist, int* __restrict__ partial, int Nn,
                     const float* __restrict__ Wmsg, const float* __restrict__ w0,
                     const float* __restrict__ w2, const float* __restrict__ Wnode,
                     float* __restrict__ W1eff, float* __restrict__ W3eff){
  __shared__ int sh[256];
  int t = threadIdx.x;
  int i = blockIdx.x*256 + t;
  sh[t] = (i < Nn) ? hist[i] : 0;
  __syncthreads();
  for (int off = 128; off > 0; off >>= 1){
    if (t < off) sh[t] += sh[t + off];
    __syncthreads();
  }
  if (t == 0) partial[blockIdx.x] = sh[0];

  // fused weight prep
  int idx = blockIdx.x*256 + t;
  if (idx < 192*128){
    int r = idx >> 7, j = idx & 127;
    float v;
    if (r < 64) v = w0[r*128 + j];
    else {
      int kk = r - 64;
      float a = 0.f;
      for (int m = 0; m < 64; m++) a = fmaf(Wmsg[kk*64 + m], w0[(64 + m)*128 + j], a);
      v = a;
    }
    W1eff[idx] = v;
  }
  if (idx < 192*64){
    int r = idx >> 6, j = idx & 63;
    W3eff[idx] = (r < 128) ? w2[r*64 + j] : Wnode[(r - 128)*64 + j];
  }
}

// single-wave exclusive scan over nb block sums
__global__ void s2_k(int* __restrict__ partial, int nb){
  int lane = threadIdx.x;  // 64 threads
  int run = 0;
  for (int base = 0; base < nb; base += 64){
    int v = (base + lane < nb) ? partial[base + lane] : 0;
    int x = v;
    #pragma unroll
    for (int off = 1; off < 64; off <<= 1){
      int y = __shfl_up(x, off);
      if (lane >= off) x += y;
    }
    if (base + lane < nb) partial[base + lane] = x - v + run;
    run += __shfl(x, 63);
  }
}

__global__ void s3_k(const int* __restrict__ hist, const int* __restrict__ partial,
                     int* __restrict__ offsets, int* __restrict__ cursor, int Nn){
  __shared__ int sh[256];
  int t = threadIdx.x;
  int i = blockIdx.x*256 + t;
  int v = (i < Nn) ? hist[i] : 0;
  sh[t] = v;
  __syncthreads();
  for (int off = 1; off < 256; off <<= 1){
    int x = (t >= off) ? sh[t - off] : 0;
    __syncthreads();
    sh[t] += x;
    __syncthreads();
  }
  if (i < Nn){
    int excl = sh[t] - v + partial[blockIdx.x];
    offsets[i] = excl;
    cursor[i]  = excl;
  }
}

// packed CSR: (edge index, sender) per slot
__global__ void fill_k(const int* __restrict__ recv, const int* __restrict__ senders,
                       int* __restrict__ cursor, int2* __restrict__ csr_pack, int E){
  int i = blockIdx.x*blockDim.x + threadIdx.x;
  if (i < E){
    int r = recv[i];
    int s = senders[i];
    int pos = atomicAdd(&cursor[r], 1);
    csr_pack[pos] = make_int2(i, s);
  }
}

// ---------------- segment sum writing TRANSPOSED via LDS ----------------
// XT layout [192][N]: rows 0..63 = nodes^T, rows 64..127 = S^T, rows 128..191 = E^T.
// Block: 512 thr = 8 waves; 64 consecutive nodes; each wave handles 8 nodes serially.
// 4 blocks/CU (LDS 33KB, threads 512) -> 32 waves/CU.
__global__ __launch_bounds__(512, 8) void gather_sum_k(
    const float* __restrict__ nodes, const float* __restrict__ edges,
    const int2* __restrict__ csr_pack, const int* __restrict__ offsets,
    const int* __restrict__ hist, float* __restrict__ XT, int Nn)
{
  __shared__ float tile[128][65];   // rows 0..63 S, 64..127 E; col = local node
  int wid  = threadIdx.x >> 6;
  int lane = threadIdx.x & 63;
  int nblock = blockIdx.x * 64;
  int nfirst = nblock + wid*8;

  // coalesced per-wave load of the 8 nodes' CSR ranges, broadcast via shfl
  int off_l = 0, cnt_l = 0;
  if (lane < 8 && nfirst + lane < Nn){
    off_l = offsets[nfirst + lane];
    cnt_l = hist[nfirst + lane];
  }

  for (int it = 0; it < 8; ++it){
    int start = __shfl(off_l, it);
    int cnt   = __shfl(cnt_l, it);
    float sa = 0.f, ea = 0.f;
    int done = 0;
    while (done < cnt){
      int m = cnt - done; if (m > 64) m = 64;
      int2 pk = make_int2(0, 0);
      if (lane < m) pk = csr_pack[start + done + lane];
      int u = 0;
      for (; u + 4 <= m; u += 4){
        int e0 = __shfl(pk.x, u+0), s0 = __shfl(pk.y, u+0);
        int e1 = __shfl(pk.x, u+1), s1 = __shfl(pk.y, u+1);
        int e2 = __shfl(pk.x, u+2), s2 = __shfl(pk.y, u+2);
        int e3 = __shfl(pk.x, u+3), s3 = __shfl(pk.y, u+3);
        float n0 = nodes[(size_t)s0*64 + lane];
        float n1 = nodes[(size_t)s1*64 + lane];
        float n2 = nodes[(size_t)s2*64 + lane];
        float n3 = nodes[(size_t)s3*64 + lane];
        float g0 = edges[(size_t)e0*64 + lane];
        float g1 = edges[(size_t)e1*64 + lane];
        float g2 = edges[(size_t)e2*64 + lane];
        float g3 = edges[(size_t)e3*64 + lane];
        sa += (n0 + n1) + (n2 + n3);
        ea += (g0 + g1) + (g2 + g3);
      }
      for (; u < m; u++){
        int e0 = __shfl(pk.x, u), s0 = __shfl(pk.y, u);
        sa += nodes[(size_t)s0*64 + lane];
        ea += edges[(size_t)e0*64 + lane];
      }
      done += m;
    }
    int c = wid*8 + it;
    tile[lane][c]      = sa;   // bank = (lane + c) % 32 -> 2-way, free
    tile[64 + lane][c] = ea;
  }
  __syncthreads();

  // coalesced transposed write-out: each wave writes one 64-float row per iter
  for (int r8 = 0; r8 < 128; r8 += 8){
    int r = r8 + wid;
    int n = nblock + lane;
    if (n < Nn) XT[(size_t)(64 + r)*Nn + n] = tile[r][lane];
  }
}

// ---------------- tiled transpose [R][C] -> [C][R] (nodes -> XT rows 0..63) ----------------
__global__ void transpose_k(const float* __restrict__ in, float* __restrict__ out, int R, int C){
  __shared__ float tl[32][33];
  int c0 = blockIdx.x*32, r0 = blockIdx.y*32;
  int tx = threadIdx.x, ty = threadIdx.y;
  #pragma unroll
  for (int i = 0; i < 32; i += 8){
    int r = r0 + ty + i, c = c0 + tx;
    if (r < R && c < C) tl[ty + i][tx] = in[(size_t)r*C + c];
  }
  __syncthreads();
  #pragma unroll
  for (int i = 0; i < 32; i += 8){
    int c = c0 + ty + i, r = r0 + tx;
    if (r < R && c < C) out[(size_t)c*R + r] = tl[tx][ty + i];
  }
}

// ---------------- MLP layers ----------------

__global__ __launch_bounds__(256) void layer1_k(
    const float* __restrict__ XT, const float* __restrict__ W, const float* __restrict__ bias,
    float* __restrict__ outT, int N)
{
  int n  = blockIdx.x*256 + threadIdx.x;
  int jb = blockIdx.y*32;
  if (n >= N) return;
  float acc[32];
  #pragma unroll
  for (int j = 0; j < 32; j++) acc[j] = bias[jb + j];
  for (int k = 0; k < 192; k++){
    float x = XT[(size_t)k*N + n];
    #pragma unroll
    for (int j = 0; j < 32; j++) acc[j] = fmaf(x, W[k*128 + jb + j], acc[j]);
  }
  #pragma unroll
  for (int j = 0; j < 32; j++) outT[(size_t)(jb + j)*N + n] = fmaxf(acc[j], 0.f);
}

__global__ __launch_bounds__(256) void layer2_k(
    const float* __restrict__ inT, const float* __restrict__ W, const float* __restrict__ bias,
    float* __restrict__ outT, int N)
{
  int n  = blockIdx.x*256 + threadIdx.x;
  int jb = blockIdx.y*32;
  if (n >= N) return;
  float acc[32];
  #pragma unroll
  for (int j = 0; j < 32; j++) acc[j] = bias[jb + j];
  for (int k = 0; k < 128; k++){
    float x = inT[(size_t)k*N + n];
    #pragma unroll
    for (int j = 0; j < 32; j++) acc[j] = fmaf(x, W[k*128 + jb + j], acc[j]);
  }
  #pragma unroll
  for (int j = 0; j < 32; j++) outT[(size_t)(jb + j)*N + n] = fmaxf(acc[j], 0.f);
}

__global__ __launch_bounds__(256) void layer3_k(
    const float* __restrict__ X2T, const float* __restrict__ nodesT,
    const float* __restrict__ W, const float* __restrict__ bias,
    const float* __restrict__ ln_scale, const float* __restrict__ ln_bias,
    float* __restrict__ out, int N)
{
  int n = blockIdx.x*256 + threadIdx.x;
  if (n >= N) return;
  float acc[64];
  #pragma unroll
  for (int j = 0; j < 64; j++) acc[j] = bias[j];
  for (int k = 0; k < 128; k++){
    float x = X2T[(size_t)k*N + n];
    #pragma unroll
    for (int j = 0; j < 64; j++) acc[j] = fmaf(x, W[k*64 + j], acc[j]);
  }
  for (int k = 0; k < 64; k++){
    float x = nodesT[(size_t)k*N + n];
    #pragma unroll
    for (int j = 0; j < 64; j++) acc[j] = fmaf(x, W[(128 + k)*64 + j], acc[j]);
  }
  float mu = 0.f;
  #pragma unroll
  for (int j = 0; j < 64; j++) mu += acc[j];
  mu *= (1.f/64.f);
  float var = 0.f;
  #pragma unroll
  for (int j = 0; j < 64; j++){ float d = acc[j] - mu; var = fmaf(d, d, var); }
  var *= (1.f/64.f);
  float inv = rsqrtf(var + 1e-6f);
  float4* o = (float4*)(out + (size_t)n*64);
  #pragma unroll
  for (int q = 0; q < 16; q++){
    float y0 = (acc[4*q+0] - mu)*inv*ln_scale[4*q+0] + ln_bias[4*q+0];
    float y1 = (acc[4*q+1] - mu)*inv*ln_scale[4*q+1] + ln_bias[4*q+1];
    float y2 = (acc[4*q+2] - mu)*inv*ln_scale[4*q+2] + ln_bias[4*q+2];
    float y3 = (acc[4*q+3] - mu)*inv*ln_scale[4*q+3] + ln_bias[4*q+3];
    o[q] = make_float4(y0, y1, y2, y3);
  }
}

// ---------------- launch ----------------

extern "C" void kernel_launch(void* const* d_in, const int* in_sizes, int n_in,
                              void* d_out, int out_size, void* d_ws, size_t ws_size,
                              hipStream_t stream)
{
  const float* nodes   = (const float*)d_in[0];
  const float* edges   = (const float*)d_in[1];
  const int*   senders = (const int*)d_in[2];
  const int*   recv    = (const int*)d_in[3];
  const float* Wmsg    = (const float*)d_in[4];
  const float* Wnode   = (const float*)d_in[5];
  const float* w0      = (const float*)d_in[6];
  const float* b0      = (const float*)d_in[7];
  const float* w1      = (const float*)d_in[8];
  const float* b1      = (const float*)d_in[9];
  const float* w2      = (const float*)d_in[10];
  const float* b2      = (const float*)d_in[11];
  const float* lns     = (const float*)d_in[12];
  const float* lnb     = (const float*)d_in[13];
  float* out = (float*)d_out;

  const int N = in_sizes[0] / 64;
  const int E = in_sizes[2];

  auto align256 = [](size_t x){ return (x + 255) & ~(size_t)255; };
  char* p = (char*)d_ws;
  int* hist    = (int*)p; p += align256((size_t)N*4);
  int* offsets = (int*)p; p += align256((size_t)N*4);
  int* cursor  = (int*)p; p += align256((size_t)N*4);
  int* partial = (int*)p; p += align256(1024);
  int2* csr_pack = (int2*)p; p += align256((size_t)E*8);
  float* W1eff = (float*)p; p += align256((size_t)192*128*4);
  float* W3eff = (float*)p; p += align256((size_t)192*64*4);
  float* XT    = (float*)p; p += align256((size_t)192*N*4);  // [nodesT; S_T; E_T]
  float* bufA  = (float*)p; p += align256((size_t)128*N*4);  // X1_T
  float* bufB  = (float*)p; p += align256((size_t)128*N*4);  // X2_T

  hipMemsetAsync(hist, 0, (size_t)N*4, stream);

  const int gridE = (E + 255)/256;
  const int nb    = (N + 255)/256;

  hist_k<<<gridE, 256, 0, stream>>>(recv, hist, E);
  s1_k<<<nb, 256, 0, stream>>>(hist, partial, N, Wmsg, w0, w2, Wnode, W1eff, W3eff);
  s2_k<<<1, 64, 0, stream>>>(partial, nb);
  s3_k<<<nb, 256, 0, stream>>>(hist, partial, offsets, cursor, N);
  fill_k<<<gridE, 256, 0, stream>>>(recv, senders, cursor, csr_pack, E);

  // nodes^T into XT rows 0..63
  dim3 tb(32, 8);
  transpose_k<<<dim3(2, (N + 31)/32), tb, 0, stream>>>(nodes, XT, N, 64);

  // S^T, E^T into XT rows 64..191 (LDS-staged transposed write)
  gather_sum_k<<<(N + 63)/64, 512, 0, stream>>>(nodes, edges, csr_pack, offsets, hist, XT, N);

  layer1_k<<<dim3(nb, 4), 256, 0, stream>>>(XT, W1eff, b0, bufA, N);
  layer2_k<<<dim3(nb, 4), 256, 0, stream>>>(bufA, w1, b1, bufB, N);
  layer3_k<<<nb, 256, 0, stream>>>(bufB, XT, W3eff, b2, lns, lnb, out, N);
}